// Round 8
// baseline (193.233 us; speedup 1.0000x reference)
//
#include <hip/hip_runtime.h>

typedef short bf16x8 __attribute__((ext_vector_type(8)));
typedef float f32x4  __attribute__((ext_vector_type(4)));
typedef unsigned int u32x2 __attribute__((ext_vector_type(2)));

#define B_SZ   2
#define T_SZ   2048
#define N_SZ   2048
#define HID_SZ 1024
#define NHEADS 16

// scale/sqrt(half) * log2(e), folded into Q at projection epilogue
#define SLOG2E 0.25500297f

static __device__ __forceinline__ float fexp2(float x) {
#if __has_builtin(__builtin_amdgcn_exp2f)
    return __builtin_amdgcn_exp2f(x);       // raw v_exp_f32
#else
    float r; __asm__("v_exp_f32 %0, %1" : "=v"(r) : "v"(x)); return r;
#endif
}

static __device__ __forceinline__ short f2bf(float f) {
    unsigned u = __float_as_uint(f);
    u = (u + 0x7fffu + ((u >> 16) & 1u)) >> 16;   // RNE
    return (short)u;
}

// pack two floats -> two bf16 (round-half-up) via v_perm_b32
static __device__ __forceinline__ unsigned pk2(float a, float b) {
#if __has_builtin(__builtin_amdgcn_perm)
    return __builtin_amdgcn_perm(__float_as_uint(b) + 0x8000u,
                                 __float_as_uint(a) + 0x8000u, 0x07060302u);
#else
    unsigned ua = (__float_as_uint(a) + 0x8000u) >> 16;
    unsigned ub = (__float_as_uint(b) + 0x8000u) & 0xffff0000u;
    return ua | ub;
#endif
}

// async global->LDS, 16B per lane; LDS dest = wave-uniform base + lane*16
static __device__ __forceinline__ void gload16(const void* g, void* l) {
    __builtin_amdgcn_global_load_lds(
        (const __attribute__((address_space(1))) unsigned int*)g,
        (__attribute__((address_space(3))) unsigned int*)l, 16, 0, 0);
}

#define MFMA16(a, b, c) __builtin_amdgcn_mfma_f32_16x16x32_bf16((a), (b), (c), 0, 0, 0)

// ---------------------------------------------------------------------------
// fp32 -> bf16 pre-convert (RNE), 8 elem/thread, all five tensors (46 MB).
// ---------------------------------------------------------------------------
__global__ __launch_bounds__(256) void cvt_kernel(
    const float* __restrict__ dec, const float* __restrict__ enc,
    const float* __restrict__ Wq, const float* __restrict__ Wk,
    const float* __restrict__ Wv,
    short* __restrict__ decb, short* __restrict__ encb,
    short* __restrict__ wqb, short* __restrict__ wkb, short* __restrict__ wvb)
{
    const float* src; short* dst; int n;
    switch (blockIdx.y) {
      case 0: src = dec; dst = decb; n = B_SZ * T_SZ * HID_SZ; break;
      case 1: src = enc; dst = encb; n = B_SZ * N_SZ * HID_SZ; break;
      case 2: src = Wq;  dst = wqb;  n = HID_SZ * HID_SZ;      break;
      case 3: src = Wk;  dst = wkb;  n = HID_SZ * HID_SZ;      break;
      default:src = Wv;  dst = wvb;  n = HID_SZ * HID_SZ;      break;
    }
    const int idx = (blockIdx.x * 256 + threadIdx.x) * 8;
    if (idx >= n) return;
    float4 a = *(const float4*)&src[idx];
    float4 b = *(const float4*)&src[idx + 4];
    bf16x8 r;
    r[0]=f2bf(a.x); r[1]=f2bf(a.y); r[2]=f2bf(a.z); r[3]=f2bf(a.w);
    r[4]=f2bf(b.x); r[5]=f2bf(b.y); r[6]=f2bf(b.z); r[7]=f2bf(b.w);
    *(bf16x8*)&dst[idx] = r;
}

// ---------------------------------------------------------------------------
// Projection GEMM, 128x128 tile, BK=64, 4 waves — PIPELINED K-loop:
//   A (bf16): reg-staged, next iter's loads issued at iter top (16 VGPR),
//             written to As between barrier#1 and a cheap barrier#2.
//   B (bf16): global_load_lds into double-buffered Bs0/Bs1, next iter's
//             prefetch issued at iter top, drained by barrier#1 AFTER the
//             32-MFMA section — the global latency that the old 2-barrier
//             shape exposed per iter now flies under compute.
// LDS: As 16 KB + Bs dbuf 32 KB = 48 KB; C-image (33.8 KB) overlays staging
// after the K-loop -> 3 blocks/CU preserved. Epilogue (round-7 verified):
// phase 1 scatter into final-layout LDS image, phase 2 full-cacheline
// 16B/lane stores (eliminates RMW read-for-write).
// Outputs (unchanged layouts):
//  proj 0: qbuf [4096,1024] row-major bf16, pre-scaled by SLOG2E
//  proj 1: kblk [(b*16+h)*32+nc][64 n][8 kg][8] — kg stored at (kg ^ (n&7))
//  proj 2: vblk [(b*16+h)*32+nc][64 vd][8 ng][8] — n' = (n&15)*4+((n>>4)&3),
//          ng stored at (ng ^ (vd&7))
// ---------------------------------------------------------------------------
__global__ __launch_bounds__(256, 3) void proj_kernel(
    const short* __restrict__ decb, const short* __restrict__ encb,
    const short* __restrict__ wqb, const short* __restrict__ wkb,
    const short* __restrict__ wvb,
    short* __restrict__ qbuf, short* __restrict__ kblk, short* __restrict__ vblk)
{
    const int i    = blockIdx.x;
    const int work = (i & 7) * 96 + (i >> 3);     // XCD-contiguous work id
    const int proj = work >> 8;
    const int rem  = work & 255;
    const int c0   = (rem >> 5) * 128;
    const int m0   = (rem & 31) * 128;

    const short* __restrict__ X = (proj == 0) ? decb : encb;
    const short* __restrict__ W = (proj == 0) ? wqb : ((proj == 1) ? wkb : wvb);

    // pool: As(8192) + Bs0(8192) + Bs1(8192) shorts in K-loop;
    // C-image (<=16896 shorts) overlays after the loop. 48 KB total.
    __shared__ short pool[24576];
    short* const As  = pool;
    short* const Bs0 = pool + 8192;
    short* const Bs1 = pool + 16384;

    const int tid  = threadIdx.x;
    const int lane = tid & 63;
    const int w    = tid >> 6;
    const int wm   = (w >> 1) * 64;
    const int wn   = (w & 1) * 64;
    const int q4   = lane >> 4;
    const int r16  = lane & 15;

    const int srow = w * 32;                       // wave stages 32 rows
    const int lrow = lane >> 3;                    // 0..7 within 8-row group
    const int lxor = (((lane & 7) ^ lrow) * 8);    // permuted k-offset (shorts)

    f32x4 acc[4][4] = {};

    // prologue: A k=0 via regs -> As; B k=0 -> Bs0 (DMA)
    {
        bf16x8 a0[4];
#pragma unroll
        for (int j = 0; j < 4; ++j) {
            const int row = srow + j * 8 + lrow;
            a0[j] = *(const bf16x8*)&X[(size_t)(m0 + row) * HID_SZ + lxor];
            gload16(&W[(size_t)(c0 + row) * HID_SZ + lxor],
                    &Bs0[(srow + j * 8) * 64]);
        }
#pragma unroll
        for (int j = 0; j < 4; ++j)
            *(bf16x8*)&As[(srow + j * 8) * 64 + lane * 8] = a0[j];
    }
    __syncthreads();   // As visible + Bs0 drained

    for (int it = 0; it < 16; ++it) {
        short* const Bcur = (it & 1) ? Bs1 : Bs0;
        short* const Bnxt = (it & 1) ? Bs0 : Bs1;

        // issue next iter's A reg-loads + B DMA; they fly under the MFMAs
        bf16x8 an[4];
        if (it < 15) {
            const int k1 = (it + 1) * 64;
#pragma unroll
            for (int j = 0; j < 4; ++j) {
                const int row = srow + j * 8 + lrow;
                an[j] = *(const bf16x8*)&X[(size_t)(m0 + row) * HID_SZ + k1 + lxor];
                gload16(&W[(size_t)(c0 + row) * HID_SZ + k1 + lxor],
                        &Bnxt[(srow + j * 8) * 64]);
            }
        }

#pragma unroll
        for (int kk = 0; kk < 2; ++kk) {
            bf16x8 af[4], bfr[4];
#pragma unroll
            for (int mi = 0; mi < 4; ++mi)
                af[mi] = *(const bf16x8*)&As[(wm + mi * 16 + r16) * 64
                                             + (((kk * 4 + q4) ^ (r16 & 7)) * 8)];
#pragma unroll
            for (int ni = 0; ni < 4; ++ni)
                bfr[ni] = *(const bf16x8*)&Bcur[(wn + ni * 16 + r16) * 64
                                                + (((kk * 4 + q4) ^ (r16 & 7)) * 8)];
#pragma unroll
            for (int mi = 0; mi < 4; ++mi)
#pragma unroll
                for (int ni = 0; ni < 4; ++ni)
                    acc[mi][ni] = MFMA16(af[mi], bfr[ni], acc[mi][ni]);
        }

        __syncthreads();   // As/Bcur reads done everywhere; prefetches drained

        if (it < 15) {
#pragma unroll
            for (int j = 0; j < 4; ++j)
                *(bf16x8*)&As[(srow + j * 8) * 64 + lane * 8] = an[j];
        }

        __syncthreads();   // As update visible (cheap: guards 4 ds_writes only)
    }

    // ---- phase 1: scatter acc into LDS image at FINAL layout positions ----
    // (loop ended on a barrier; staging region is dead, safe to overlay)
    if (proj == 0) {
        // image: [row 0..127][col 0..127], row stride 132 (bank stagger)
#pragma unroll
        for (int mi = 0; mi < 4; ++mi)
#pragma unroll
        for (int ni = 0; ni < 4; ++ni)
#pragma unroll
        for (int r = 0; r < 4; ++r) {
            const int tr = wm + mi * 16 + q4 * 4 + r;
            const int cc = wn + ni * 16 + r16;
            pool[tr * 132 + cc] = f2bf(acc[mi][ni][r] * SLOG2E);
        }
    } else if (proj == 1) {
        // 4 blobs of 4096 shorts; each wave fills exactly one blob
        const int bl = ((wn >> 6) << 1) | (wm >> 6);
#pragma unroll
        for (int mi = 0; mi < 4; ++mi)
#pragma unroll
        for (int ni = 0; ni < 4; ++ni)
#pragma unroll
        for (int r = 0; r < 4; ++r) {
            const int row64 = mi * 16 + q4 * 4 + r;     // n & 63
            const int kd    = ni * 16 + r16;            // c & 63
            const int j = ((((kd >> 3) ^ (row64 & 7)) << 3) | (kd & 7));
            pool[bl * 4096 + row64 * 64 + j] = f2bf(acc[mi][ni][r]);
        }
    } else {
        const int bl = ((wn >> 6) << 1) | (wm >> 6);
#pragma unroll
        for (int mi = 0; mi < 4; ++mi)
#pragma unroll
        for (int ni = 0; ni < 4; ++ni)
#pragma unroll
        for (int r = 0; r < 4; ++r) {
            const int nl = mi * 16 + q4 * 4 + r;        // n & 63
            const int vd = ni * 16 + r16;               // c & 63
            const int np = ((nl & 15) << 2) | ((nl >> 4) & 3);
            const int j = ((((np >> 3) ^ (vd & 7)) << 3) | (np & 7));
            pool[bl * 4096 + vd * 64 + j] = f2bf(acc[mi][ni][r]);
        }
    }

    __syncthreads();   // image complete

    // ---- phase 2: lane-contiguous full-line LDS -> global copy ----
    if (proj == 0) {
        const int c16 = tid & 15;                 // 16 lanes x 16B = 256B/row
#pragma unroll
        for (int rnd = 0; rnd < 8; ++rnd) {
            const int row = rnd * 16 + (tid >> 4);
            *(bf16x8*)&qbuf[(size_t)(m0 + row) * HID_SZ + c0 + c16 * 8] =
                *(const bf16x8*)&pool[row * 132 + c16 * 8];
        }
    } else {
        short* __restrict__ dst = (proj == 1) ? kblk : vblk;
        const int bb  = m0 >> 11;
        const int hh0 = c0 >> 6;
        const int nc0 = (m0 >> 6) & 31;
#pragma unroll
        for (int bl = 0; bl < 4; ++bl) {
            const size_t base =
                ((size_t)((bb * NHEADS + hh0 + (bl >> 1)) * 32
                          + nc0 + (bl & 1))) * 4096;
#pragma unroll
            for (int r2 = 0; r2 < 2; ++r2) {
                const int s = (r2 * 256 + tid) * 8;   // 256 thr x 16B = 4KB
                *(bf16x8*)&dst[base + s] = *(const bf16x8*)&pool[bl * 4096 + s];
            }
        }
    }
}

// ---------------------------------------------------------------------------
// One 16-row t-slice of the differential attention chunk compute:
// QK^T -> exp2/pack -> wave-private P in LDS -> PV + l. (round-1 verified
// math/layout) + s_setprio(1) around the MFMA clusters (m191 regime: 16
// decorrelated waves/CU give the scheduler something to arbitrate).
// ---------------------------------------------------------------------------
static __device__ __forceinline__ void attn_half(
    const short* __restrict__ Ks, const short* __restrict__ Vs,
    short* __restrict__ P,
    bf16x8 aq1, bf16x8 aq2, bf16x8 ones,
    f32x4 (&o0)[4], f32x4 (&o1)[4], f32x4& l0a, f32x4& l1a,
    int q4, int r16, int swz, int wg_half, int wlo)
{
    // QK from LDS
    const f32x4 zz = {0.f, 0.f, 0.f, 0.f};
    f32x4 s0[4], s1[4];
    __builtin_amdgcn_s_setprio(1);
#pragma unroll
    for (int s = 0; s < 4; ++s) {
        const int row = s * 16 + r16;
        bf16x8 bk1 = *(const bf16x8*)&Ks[row * 64 + ((q4 ^ swz) << 3)];
        bf16x8 bk2 = *(const bf16x8*)&Ks[row * 64 + (((4 + q4) ^ swz) << 3)];
        s0[s] = MFMA16(aq1, bk1, zz);
        s1[s] = MFMA16(aq2, bk2, zz);
    }
    __builtin_amdgcn_s_setprio(0);

    // exp2 + pack + wave-private LDS stage
#pragma unroll
    for (int r = 0; r < 4; ++r) {
        const int row = q4 * 4 + r;
        const int wo  = row * 64 + ((wg_half ^ (row & 7)) << 3) + wlo;
        u32x2 pw;
        pw[0] = pk2(fexp2(s0[0][r]), fexp2(s0[1][r]));
        pw[1] = pk2(fexp2(s0[2][r]), fexp2(s0[3][r]));
        *(u32x2*)&P[wo] = pw;
        pw[0] = pk2(fexp2(s1[0][r]), fexp2(s1[1][r]));
        pw[1] = pk2(fexp2(s1[2][r]), fexp2(s1[3][r]));
        *(u32x2*)&P[1024 + wo] = pw;
    }

    // PV + l from LDS (same-wave ds ordering makes P write->read safe)
    __builtin_amdgcn_s_setprio(1);
#pragma unroll
    for (int kk = 0; kk < 2; ++kk) {
        const int ro = r16 * 64 + (((kk * 4 + q4) ^ swz) << 3);
        bf16x8 ap0 = *(const bf16x8*)&P[ro];
        bf16x8 ap1 = *(const bf16x8*)&P[1024 + ro];
        l0a = MFMA16(ap0, ones, l0a);
        l1a = MFMA16(ap1, ones, l1a);
#pragma unroll
        for (int d = 0; d < 4; ++d) {
            const int vd = d * 16 + r16;
            bf16x8 bv = *(const bf16x8*)&Vs[vd * 64 + (((kk * 4 + q4) ^ swz) << 3)];
            o0[d] = MFMA16(ap0, bv, o0[d]);
            o1[d] = MFMA16(ap1, bv, o1[d]);
        }
    }
    __builtin_amdgcn_s_setprio(0);
}

// ---------------------------------------------------------------------------
// Differential flash attention, 8-wave blocks (round-5 verified structure).
// ---------------------------------------------------------------------------
__global__ __launch_bounds__(512, 4) void attn_kernel(
    const short* __restrict__ qbuf, const short* __restrict__ kblk,
    const short* __restrict__ vblk,
    const float* __restrict__ lq1, const float* __restrict__ lq2,
    const float* __restrict__ lk1, const float* __restrict__ lk2,
    float* __restrict__ out)
{
    const int bi   = blockIdx.x;
    const int work = (bi & 7) * 64 + (bi >> 3);   // XCD-contiguous, 512 blocks
    const int t0   = (work & 15) * 128;
    const int hb   = work >> 4;
    const int h    = hb & 15;
    const int b    = hb >> 4;

    const int tid  = threadIdx.x;
    const int w    = tid >> 6;          // 0..7
    const int lane = tid & 63;
    const int q4   = lane >> 4;
    const int r16  = lane & 15;

    float d1 = 0.f, d2 = 0.f;
#pragma unroll
    for (int i = 0; i < 32; ++i) { d1 += lq1[i] * lk1[i]; d2 += lq2[i] * lk2[i]; }
    const float lam = __expf(d1) - __expf(d2) + 0.8f;

    __shared__ short Ks[2][4096];     // 16 KB double-buffered K
    __shared__ short Vs[2][4096];     // 16 KB double-buffered V
    __shared__ short Pl[8][2048];     // 32 KB per-wave P (2 comps x 16 x 64)
    short* __restrict__ P = &Pl[w][0];

    const int trow = t0 + w * 16 + r16;
    const short* qrow = qbuf + ((size_t)(b * T_SZ + trow)) * HID_SZ + h * 64;
    const bf16x8 aq1 = *(const bf16x8*)(qrow + q4 * 8);
    const bf16x8 aq2 = *(const bf16x8*)(qrow + 32 + q4 * 8);

    const short* kbh = kblk + ((size_t)(b * NHEADS + h)) * 32 * 4096;
    const short* vbh = vblk + ((size_t)(b * NHEADS + h)) * 32 * 4096;

    bf16x8 ones;
#pragma unroll
    for (int i = 0; i < 8; ++i) ones[i] = (short)0x3F80;   // bf16 1.0

    f32x4 o0[4] = {}, o1[4] = {};
    f32x4 l0a = {0.f,0.f,0.f,0.f}, l1a = {0.f,0.f,0.f,0.f};

    const int wg_half = (r16 >> 1);
    const int wlo     = (r16 & 1) * 4;
    const int swz     = r16 & 7;      // fragment-read unswizzle

    // prologue: stage chunk 0 into buffer 0 (8 waves x 1KB each for K and V)
    gload16(&kbh[w * 512 + lane * 8], &Ks[0][w * 512]);
    gload16(&vbh[w * 512 + lane * 8], &Vs[0][w * 512]);
    __syncthreads();   // drain: chunk 0 ready

    for (int nc = 0; nc < 32; ++nc) {
        const int cur = nc & 1;

        // prefetch chunk nc+1 into the other buffer; drained by the
        // end-of-chunk barrier, so it flies under this chunk's compute.
        if (nc + 1 < 32) {
            const short* Kg = kbh + (nc + 1) * 4096;
            const short* Vg = vbh + (nc + 1) * 4096;
            gload16(&Kg[w * 512 + lane * 8], &Ks[cur ^ 1][w * 512]);
            gload16(&Vg[w * 512 + lane * 8], &Vs[cur ^ 1][w * 512]);
        }

        attn_half(Ks[cur], Vs[cur], P, aq1, aq2, ones, o0, o1, l0a, l1a,
                  q4, r16, swz, wg_half, wlo);

        __syncthreads();   // drain prefetch + all waves done with cur
    }

    float rl0[4], rl1[4];
#pragma unroll
    for (int r = 0; r < 4; ++r) { rl0[r] = 1.f / l0a[r]; rl1[r] = lam / l1a[r]; }

#pragma unroll
    for (int d = 0; d < 4; ++d)
#pragma unroll
        for (int r = 0; r < 4; ++r) {
            const int t  = t0 + w * 16 + q4 * 4 + r;
            const int vd = d * 16 + r16;
            out[((size_t)(b * T_SZ + t)) * HID_SZ + h * 64 + vd] =
                o0[d][r] * rl0[r] - o1[d][r] * rl1[r];
        }
}

extern "C" void kernel_launch(void* const* d_in, const int* in_sizes, int n_in,
                              void* d_out, int out_size, void* d_ws, size_t ws_size,
                              hipStream_t stream)
{
    (void)in_sizes; (void)n_in; (void)out_size; (void)ws_size;

    const float* enc = (const float*)d_in[0];
    const float* dec = (const float*)d_in[1];
    const float* Wq  = (const float*)d_in[2];
    const float* Wk  = (const float*)d_in[3];
    const float* Wv  = (const float*)d_in[4];
    const float* lq1 = (const float*)d_in[5];
    const float* lq2 = (const float*)d_in[6];
    const float* lk1 = (const float*)d_in[7];
    const float* lk2 = (const float*)d_in[8];
    float* out = (float*)d_out;

    short* qbuf = (short*)d_ws;                          // [4096,1024]
    short* kblk = qbuf + (size_t)4096 * 1024;            // [32 bh][32 nc][4096]
    short* vblk = kblk + (size_t)4096 * 1024;            // [32 bh][32 nc][4096]
    short* decb = vblk + (size_t)4096 * 1024;            // [2,2048,1024]
    short* encb = decb + (size_t)2 * 2048 * 1024;        // [2,2048,1024]
    short* wqb  = encb + (size_t)2 * 2048 * 1024;        // [1024,1024]
    short* wkb  = wqb  + (size_t)1024 * 1024;
    short* wvb  = wkb  + (size_t)1024 * 1024;

    cvt_kernel<<<dim3(2048, 5), 256, 0, stream>>>(
        dec, enc, Wq, Wk, Wv, decb, encb, wqb, wkb, wvb);

    proj_kernel<<<768, 256, 0, stream>>>(
        decb, encb, wqb, wkb, wvb, qbuf, kblk, vblk);

    attn_kernel<<<512, 512, 0, stream>>>(
        qbuf, kblk, vblk, lq1, lq2, lk1, lk2, out);
}